// Round 13
// baseline (2987.425 us; speedup 1.0000x reference)
//
#include <hip/hip_runtime.h>
#include <hip/hip_bf16.h>

// ---------- types & helpers ----------
typedef __attribute__((ext_vector_type(8))) short bf16x8;
typedef __attribute__((ext_vector_type(4))) float f32x4;

__device__ __forceinline__ short f2bf(float f) {
  unsigned u = __float_as_uint(f);
  u = u + 0x7fffu + ((u >> 16) & 1u);   // RNE
  return (short)(u >> 16);
}
__device__ __forceinline__ float bf2f(short s) {
  return __uint_as_float(((unsigned)(unsigned short)s) << 16);
}

#define GLOB_CAST(p) ((const __attribute__((address_space(1))) void*)(p))
#define LDS_CAST(p) ((__attribute__((address_space(3))) void*)(p))
#define GLL16(g, l) __builtin_amdgcn_global_load_lds(GLOB_CAST(g), LDS_CAST(l), 16, 0, 0)

constexpr int EP_BF16 = 0, EP_SCORES = 1, EP_DYT = 2, EP_GELU = 3, EP_PRIOR = 4;

// ---------- fp32 -> bf16 convert ----------
__global__ __launch_bounds__(256) void cvt_k(const float* __restrict__ src,
                                             short* __restrict__ dst, long n4) {
  const long s = (long)blockIdx.x * 256 + threadIdx.x;
  if (s >= n4) return;
  float4 v = ((const float4*)src)[s];
  short4 o = {f2bf(v.x), f2bf(v.y), f2bf(v.z), f2bf(v.w)};
  ((short4*)dst)[s] = o;
}

// convert one layer's 6 weight mats into contiguous bf16 buffer (layer 0 only;
// layers 1..11 are converted inside tail_cvt_k of the previous layer).
// Per-layer on purpose: LW written right before use stays L2/LLC-hot.
// (one-shot cvt_all was a persistent ~200us regression R5-R8: cold re-reads.)
__global__ __launch_bounds__(256) void cvt_layer_k(
    const float* __restrict__ wq, const float* __restrict__ wk,
    const float* __restrict__ wv, const float* __restrict__ wp,
    const float* __restrict__ we, const float* __restrict__ wc,
    short* __restrict__ dst) {
  const long s = (long)blockIdx.x * 256 + threadIdx.x;  // 1,769,472 total
  const long e = s * 4;
  const float* src; long off;
  if (e < 589824)        { src = wq; off = e; }
  else if (e < 1179648)  { src = wk; off = e - 589824; }
  else if (e < 1769472)  { src = wv; off = e - 1179648; }
  else if (e < 2359296)  { src = wp; off = e - 1769472; }
  else if (e < 4718592)  { src = we; off = e - 2359296; }
  else                   { src = wc; off = e - 4718592; }
  float4 v = *(const float4*)(src + off);
  short4 o = {f2bf(v.x), f2bf(v.y), f2bf(v.z), f2bf(v.w)};
  *(short4*)(dst + e) = o;
}

// ---------- embedding gather fused with layer-0 head ----------
__global__ __launch_bounds__(256) void embed_head_k(
    const int* __restrict__ idx, const float* __restrict__ wte,
    const float* __restrict__ pos, const float* __restrict__ alp,
    const float* __restrict__ w, const float* __restrict__ b,
    float* __restrict__ x, float* __restrict__ prior, short* __restrict__ h) {
  const long s = (long)blockIdx.x * 256 + threadIdx.x;  // 786432 float4 slots
  const long row = s / 192;
  const int c4 = (int)(s % 192);
  float4 xv = ((const float4*)(wte + (long)idx[row] * 768))[c4];
  ((float4*)x)[s] = xv;
  float4 pv = ((const float4*)pos)[c4];
  float4 w0 = ((const float4*)w)[c4];
  float4 b0 = ((const float4*)b)[c4];
  float4 w2 = ((const float4*)(w + 1536))[c4];
  float4 b2 = ((const float4*)(b + 1536))[c4];
  const float a0 = alp[0], a2 = alp[2];
  float4 xl = {xv.x + pv.x, xv.y + pv.y, xv.z + pv.z, xv.w + pv.w};
  float4 pr = {tanhf(a2 * xl.x) * w2.x + b2.x, tanhf(a2 * xl.y) * w2.y + b2.y,
               tanhf(a2 * xl.z) * w2.z + b2.z, tanhf(a2 * xl.w) * w2.w + b2.w};
  ((float4*)prior)[s] = pr;
  short4 hh = {f2bf(tanhf(a0 * xl.x) * w0.x + b0.x),
               f2bf(tanhf(a0 * xl.y) * w0.y + b0.y),
               f2bf(tanhf(a0 * xl.z) * w0.z + b0.z),
               f2bf(tanhf(a0 * xl.w) * w0.w + b0.w)};
  ((short4*)h)[s] = hh;
}

// ---------- generic C = A * B^T GEMM, 128xTN tile, BK=64 (R3/R9-proven config) ----------
// T2 XOR-swizzled LDS both sides -> 0 bank conflicts (verified R2).
// TN=64 for ALL layer GEMMs now (R12->R13): halves Bs LDS (24KB/block ->
// more resident blocks) and doubles grid -> more wave-level overlap of the
// per-K-step vmcnt(0)+barrier drains; extra B re-reads are L2-resident.
template <int EP, int TN>
__global__ __launch_bounds__(256, 2) void gemm_bt(
    const short* __restrict__ A, const short* __restrict__ B,
    void* __restrict__ Cv, int K, int lda, int ldb, int ldc,
    long sA, long sB, long sC,
    const float* __restrict__ bias, const float* __restrict__ dw,
    const float* __restrict__ db, const float* __restrict__ alp,
    const float* __restrict__ prior, float scale) {
  constexpr int NF = TN / 32;            // col frags per wave (4 or 2)
  __shared__ short As[128 * 64];
  __shared__ short Bs[TN * 64];
  const int tid = threadIdx.x, lane = tid & 63;
  const int wr = tid >> 7, wc = (tid >> 6) & 1;
  const long rowBase = (long)blockIdx.y * 128;
  const long colBase = (long)blockIdx.x * TN;
  const short* Ab = A + (long)blockIdx.z * sA;
  const short* Bb = B + (long)blockIdx.z * sB;
  const int srow = tid >> 3, sseg = tid & 7;
  const int ssegS = sseg ^ (srow & 7);    // pre-swizzled source column unit

  f32x4 acc[4][NF];
#pragma unroll
  for (int m = 0; m < 4; ++m)
#pragma unroll
    for (int n = 0; n < NF; ++n) acc[m][n] = (f32x4){0.f, 0.f, 0.f, 0.f};

  const int q = lane >> 4, cl = lane & 15;
  const int rsw = cl & 7;

  for (int kt = 0; kt < K; kt += 64) {
#pragma unroll
    for (int i = 0; i < 4; ++i)
      GLL16(Ab + (rowBase + i * 32 + srow) * (long)lda + kt + ssegS * 8,
            As + ((i * 32 + srow) * 64 + sseg * 8));
#pragma unroll
    for (int i = 0; i < TN / 32; ++i)
      GLL16(Bb + (colBase + i * 32 + srow) * (long)ldb + kt + ssegS * 8,
            Bs + ((i * 32 + srow) * 64 + sseg * 8));
    __syncthreads();
#pragma unroll
    for (int kk = 0; kk < 2; ++kk) {
      const int sw = ((kk * 4 + q) ^ rsw) << 3;   // swizzled short offset
      bf16x8 af[4], bfr[NF];
#pragma unroll
      for (int m = 0; m < 4; ++m)
        af[m] = *(const bf16x8*)&As[(wr * 64 + m * 16 + cl) * 64 + sw];
#pragma unroll
      for (int n = 0; n < NF; ++n)
        bfr[n] = *(const bf16x8*)&Bs[(wc * (TN / 2) + n * 16 + cl) * 64 + sw];
#pragma unroll
      for (int m = 0; m < 4; ++m)
#pragma unroll
        for (int n = 0; n < NF; ++n)
          acc[m][n] = __builtin_amdgcn_mfma_f32_16x16x32_bf16(af[m], bfr[n], acc[m][n], 0, 0, 0);
    }
    __syncthreads();
  }

#pragma unroll
  for (int m = 0; m < 4; ++m) {
#pragma unroll
    for (int n = 0; n < NF; ++n) {
#pragma unroll
      for (int j = 0; j < 4; ++j) {
        long r = rowBase + wr * 64 + m * 16 + q * 4 + j;
        long c = colBase + wc * (TN / 2) + n * 16 + cl;
        float v = acc[m][n][j];
        if constexpr (EP == EP_SCORES) {
          // bf16 of v*scale only (O(0.4), bf16-safe). ALiBi bias -|t-c| is
          // index-deterministic (up to -1023, NOT bf16-safe) and is
          // reconstructed exactly in softmax.
          ((short*)Cv)[(long)blockIdx.z * sC + r * ldc + c] = f2bf(v * scale);
        } else if constexpr (EP == EP_BF16) {
          ((short*)Cv)[(long)blockIdx.z * sC + r * ldc + c] = f2bf(v);
        } else if constexpr (EP == EP_DYT) {
          float xv = v + bias[c];
          ((short*)Cv)[r * (long)ldc + c] = f2bf(tanhf(alp[0] * xv) * dw[c] + db[c]);
        } else if constexpr (EP == EP_GELU) {
          float xv = v + bias[c];
          ((short*)Cv)[r * (long)ldc + c] = f2bf(0.5f * xv * (1.f + erff(xv * 0.70710678118654752f)));
        } else if constexpr (EP == EP_PRIOR) {
          ((float*)Cv)[r * (long)ldc + c] = v + bias[c] + prior[r * (long)ldc + c];
        }
      }
    }
  }
}

// ---------- fused: softmax (blocks 0..1023) + V transpose (blocks 1024..4095) ----------
__global__ __launch_bounds__(256) void softmax_transp_k(
    short* __restrict__ sc, const short* __restrict__ qkvb,
    short* __restrict__ vt) {
  if (blockIdx.x < 1024) {
    // softmax over 1024 bf16 scores, ALiBi bias reconstructed, in place
    const int lane = threadIdx.x & 63;
    const long row = (long)blockIdx.x * 4 + (threadIdx.x >> 6);
    const int t = (int)(row & 1023);
    short* p = sc + row * 1024;
    const int c0 = lane * 16;
    bf16x8 a = *(const bf16x8*)(p + c0);
    bf16x8 b = *(const bf16x8*)(p + c0 + 8);
    float v[16];
    float mx = -3e38f;
#pragma unroll
    for (int i = 0; i < 8; ++i) {
      v[i] = bf2f(a[i]) - fabsf((float)(t - (c0 + i)));
      v[i + 8] = bf2f(b[i]) - fabsf((float)(t - (c0 + 8 + i)));
    }
#pragma unroll
    for (int i = 0; i < 16; ++i) mx = fmaxf(mx, v[i]);
#pragma unroll
    for (int o = 1; o < 64; o <<= 1) mx = fmaxf(mx, __shfl_xor(mx, o));
    float e[16];
    float s = 0.f;
#pragma unroll
    for (int i = 0; i < 16; ++i) { e[i] = __expf(v[i] - mx); s += e[i]; }
#pragma unroll
    for (int o = 1; o < 64; o <<= 1) s += __shfl_xor(s, o);
    const float inv = 1.f / s;
    bf16x8 o0, o1;
#pragma unroll
    for (int i = 0; i < 8; ++i) {
      o0[i] = f2bf(e[i] * inv);
      o1[i] = f2bf(e[i + 8] * inv);
    }
    *(bf16x8*)(p + c0) = o0;
    *(bf16x8*)(p + c0 + 8) = o1;
  } else {
    // V transpose: (b,1024, cols 1536..2303 of QKVB) -> (b,768,1024)
    __shared__ short tbuf[32][33];
    const int t = blockIdx.x - 1024;          // 0..3071
    const int b = t & 3;
    const int rest = t >> 2;                  // 0..767
    const int d0 = (rest % 24) * 32, t0 = (rest / 24) * 32;
    const int tx = threadIdx.x & 31, ty = threadIdx.x >> 5;
    const short* Vb = qkvb + (long)b * 1024 * 2304 + 1536;
    short* Tb = vt + (long)b * 768 * 1024;
#pragma unroll
    for (int i = 0; i < 4; ++i)
      tbuf[ty + i * 8][tx] = Vb[(long)(t0 + ty + i * 8) * 2304 + d0 + tx];
    __syncthreads();
#pragma unroll
    for (int i = 0; i < 4; ++i)
      Tb[(long)(d0 + ty + i * 8) * 1024 + t0 + tx] = tbuf[tx][ty + i * 8];
  }
}

// ---------- fused tail: KL + next-layer head (blocks 0..1023) +
//            next-layer weight cvt (blocks 1024..7935) ----------
__global__ __launch_bounds__(256) void tail_cvt_k(
    float* __restrict__ prior, const float* __restrict__ post,
    const float* __restrict__ pos_n, const float* __restrict__ alp_n,
    const float* __restrict__ w_n, const float* __restrict__ b_n,
    short* __restrict__ h, short* __restrict__ xbf,
    double* __restrict__ acc, int last,
    const float* __restrict__ wq, const float* __restrict__ wk,
    const float* __restrict__ wv, const float* __restrict__ wp,
    const float* __restrict__ we, const float* __restrict__ wc,
    short* __restrict__ lwdst) {
  if (blockIdx.x >= 1024) {
    if (last) return;
    const long s = (long)(blockIdx.x - 1024) * 256 + threadIdx.x;  // 1,769,472
    const long e = s * 4;
    const float* src; long off;
    if (e < 589824)        { src = wq; off = e; }
    else if (e < 1179648)  { src = wk; off = e - 589824; }
    else if (e < 1769472)  { src = wv; off = e - 1179648; }
    else if (e < 2359296)  { src = wp; off = e - 1769472; }
    else if (e < 4718592)  { src = we; off = e - 2359296; }
    else                   { src = wc; off = e - 4718592; }
    float4 v = *(const float4*)(src + off);
    short4 o = {f2bf(v.x), f2bf(v.y), f2bf(v.z), f2bf(v.w)};
    *(short4*)(lwdst + e) = o;
    return;
  }
  const int lane = threadIdx.x & 63;
  const long row = (long)blockIdx.x * 4 + (threadIdx.x >> 6);
  float* pp = prior + row * 768;
  const float* qq = post + row * 768;
  float p[12], q[12];
#pragma unroll
  for (int i = 0; i < 12; ++i) { p[i] = pp[lane + i * 64]; q[i] = qq[lane + i * 64]; }
  float mp = -3e38f, mq = -3e38f, mm = -3e38f;
#pragma unroll
  for (int i = 0; i < 12; ++i) {
    float m = 0.5f * (p[i] + q[i]);
    mp = fmaxf(mp, p[i]); mq = fmaxf(mq, q[i]); mm = fmaxf(mm, m);
  }
#pragma unroll
  for (int o = 1; o < 64; o <<= 1) {
    mp = fmaxf(mp, __shfl_xor(mp, o));
    mq = fmaxf(mq, __shfl_xor(mq, o));
    mm = fmaxf(mm, __shfl_xor(mm, o));
  }
  float sp = 0.f, sq = 0.f, sm = 0.f;
#pragma unroll
  for (int i = 0; i < 12; ++i) {
    sp += __expf(p[i] - mp);
    sq += __expf(q[i] - mq);
    sm += __expf(0.5f * (p[i] + q[i]) - mm);
  }
#pragma unroll
  for (int o = 1; o < 64; o <<= 1) {
    sp += __shfl_xor(sp, o); sq += __shfl_xor(sq, o); sm += __shfl_xor(sm, o);
  }
  const float lseP = mp + logf(sp), lseQ = mq + logf(sq), lseM = mm + logf(sm);
  float kl = 0.f;
#pragma unroll
  for (int i = 0; i < 12; ++i) {
    float m = 0.5f * (p[i] + q[i]);
    float lm = m - lseM;
    kl += __expf(lm) * (2.f * lm - (p[i] - lseP) - (q[i] - lseQ));
  }
#pragma unroll
  for (int o = 1; o < 64; o <<= 1) kl += __shfl_xor(kl, o);
  if (lane == 0) atomicAdd(&acc[0], (double)kl);

  if (last) {
#pragma unroll
    for (int i = 0; i < 12; ++i) xbf[row * 768 + lane + i * 64] = f2bf(q[i]);
  } else {
    const float a0 = alp_n[0], a2 = alp_n[2];
#pragma unroll
    for (int i = 0; i < 12; ++i) {
      const int col = lane + i * 64;
      float xl = q[i] + pos_n[col];
      pp[col] = tanhf(a2 * xl) * w_n[1536 + col] + b_n[1536 + col];
      h[row * 768 + col] = f2bf(tanhf(a0 * xl) * w_n[col] + b_n[col]);
    }
  }
}

// ---------- vocab GEMM with online logsumexp + last-token logits ----------
__global__ __launch_bounds__(256, 2) void lse_gemm_k(
    const short* __restrict__ Xb, const short* __restrict__ Wt,
    float* __restrict__ pm, float* __restrict__ ps,
    float* __restrict__ logits_out, int G) {
  __shared__ short As[128 * 64];
  __shared__ short Bs[128 * 64];
  __shared__ float pmx[2][128], psm[2][128], rm[128], rs[128];
  const int tid = threadIdx.x, lane = tid & 63;
  const int wr = tid >> 7, wc = (tid >> 6) & 1;
  const int g = blockIdx.x;
  const long rowBase = (long)blockIdx.y * 128;
  const int srow = tid >> 3, sseg = tid & 7;
  const int ssegS = sseg ^ (srow & 7);
  const int q = lane >> 4, cl = lane & 15;
  const int rsw = cl & 7;
  if (tid < 128) { rm[tid] = -3e38f; rs[tid] = 0.f; }

  for (int tile = g; tile < 393; tile += G) {
    const long colBase = (long)tile * 128;
    f32x4 acc[4][4];
#pragma unroll
    for (int m = 0; m < 4; ++m)
#pragma unroll
      for (int n = 0; n < 4; ++n) acc[m][n] = (f32x4){0.f, 0.f, 0.f, 0.f};

    for (int kt = 0; kt < 768; kt += 64) {
#pragma unroll
      for (int i = 0; i < 4; ++i) {
        GLL16(Xb + (rowBase + i * 32 + srow) * 768L + kt + ssegS * 8,
              As + ((i * 32 + srow) * 64 + sseg * 8));
        GLL16(Wt + (colBase + i * 32 + srow) * 768L + kt + ssegS * 8,
              Bs + ((i * 32 + srow) * 64 + sseg * 8));
      }
      __syncthreads();
#pragma unroll
      for (int kk = 0; kk < 2; ++kk) {
        const int sw = ((kk * 4 + q) ^ rsw) << 3;
        bf16x8 af[4], bfr[4];
#pragma unroll
        for (int m = 0; m < 4; ++m)
          af[m] = *(const bf16x8*)&As[(wr * 64 + m * 16 + cl) * 64 + sw];
#pragma unroll
        for (int n = 0; n < 4; ++n)
          bfr[n] = *(const bf16x8*)&Bs[(wc * 64 + n * 16 + cl) * 64 + sw];
#pragma unroll
        for (int m = 0; m < 4; ++m)
#pragma unroll
          for (int n = 0; n < 4; ++n)
            acc[m][n] = __builtin_amdgcn_mfma_f32_16x16x32_bf16(af[m], bfr[n], acc[m][n], 0, 0, 0);
      }
      __syncthreads();
    }

    // last-token logits straight to d_out
#pragma unroll
    for (int m = 0; m < 4; ++m)
#pragma unroll
      for (int n = 0; n < 4; ++n)
#pragma unroll
        for (int j = 0; j < 4; ++j) {
          long r = rowBase + wr * 64 + m * 16 + q * 4 + j;
          if ((r & 1023) == 1023) {
            long c = colBase + wc * 64 + n * 16 + cl;
            logits_out[(r >> 10) * 50304 + c] = acc[m][n][j];
          }
        }

    // per-row stats over this 128-col tile
#pragma unroll
    for (int m = 0; m < 4; ++m) {
#pragma unroll
      for (int j = 0; j < 4; ++j) {
        float mx = acc[m][0][j];
#pragma unroll
        for (int n = 1; n < 4; ++n) mx = fmaxf(mx, acc[m][n][j]);
#pragma unroll
        for (int o = 1; o < 16; o <<= 1) mx = fmaxf(mx, __shfl_xor(mx, o));
        float sm = 0.f;
#pragma unroll
        for (int n = 0; n < 4; ++n) sm += __expf(acc[m][n][j] - mx);
#pragma unroll
        for (int o = 1; o < 16; o <<= 1) sm += __shfl_xor(sm, o);
        if (cl == 0) {
          int lr = wr * 64 + m * 16 + q * 4 + j;
          pmx[wc][lr] = mx;
          psm[wc][lr] = sm;
        }
      }
    }
    __syncthreads();
    if (tid < 128) {
      float m0 = pmx[0][tid], m1 = pmx[1][tid];
      float m2 = fmaxf(m0, m1);
      float s2 = psm[0][tid] * __expf(m0 - m2) + psm[1][tid] * __expf(m1 - m2);
      float mo = rm[tid], mn = fmaxf(mo, m2);
      rs[tid] = rs[tid] * __expf(mo - mn) + s2 * __expf(m2 - mn);
      rm[tid] = mn;
    }
    __syncthreads();
  }
  if (tid < 128) {
    long row = rowBase + tid;
    pm[row * G + g] = rm[tid];
    ps[row * G + g] = rs[tid];
  }
}

// ---------- target logit: dot(x[row], wte[target[row]]) ----------
__global__ __launch_bounds__(256) void tlog_k(const short* __restrict__ xbf,
                                              const short* __restrict__ wtebf,
                                              const int* __restrict__ targets,
                                              float* __restrict__ tlog) {
  const int lane = threadIdx.x & 63;
  const long row = (long)blockIdx.x * 4 + (threadIdx.x >> 6);
  const long tgt = targets[row];
  const short* a = xbf + row * 768;
  const short* b = wtebf + tgt * 768;
  float s = 0.f;
#pragma unroll
  for (int i = 0; i < 12; ++i) s += bf2f(a[lane + i * 64]) * bf2f(b[lane + i * 64]);
#pragma unroll
  for (int o = 1; o < 64; o <<= 1) s += __shfl_xor(s, o);
  if (lane == 0) tlog[row] = s;
}

// ---------- combine split-lse partials, accumulate nll ----------
__global__ __launch_bounds__(256) void stage2_k(const float* __restrict__ pm,
                                                const float* __restrict__ ps,
                                                const float* __restrict__ tlog,
                                                double* __restrict__ acc, int G) {
  const long row = (long)blockIdx.x * 256 + threadIdx.x;
  float M = -3e38f;
  for (int gi = 0; gi < G; ++gi) M = fmaxf(M, pm[row * G + gi]);
  float S = 0.f;
  for (int gi = 0; gi < G; ++gi) S += ps[row * G + gi] * __expf(pm[row * G + gi] - M);
  float nll = (M + logf(S)) - tlog[row];
#pragma unroll
  for (int o = 1; o < 64; o <<= 1) nll += __shfl_xor(nll, o);
  if ((threadIdx.x & 63) == 0) atomicAdd(&acc[1], (double)nll);
}

__global__ void finalize_k(const double* __restrict__ acc, float* __restrict__ out) {
  if (threadIdx.x == 0)
    out[201216] = (float)(acc[1] / 4096.0 + 0.1 * 0.5 * acc[0] / 4.0);
}

// ---------- workspace layout (bytes) ----------
constexpr size_t OFF_WTEBF = 0;                       // 77,266,944
constexpr size_t OFF_LW    = 77266944;                // 2 x 14,155,776 (double-buffered)
constexpr size_t OFF_X     = 105578496;               // 12,582,912
constexpr size_t OFF_PRIOR = 118161408;               // 12,582,912
constexpr size_t OFF_HB    = 130744320;               //  6,291,456 (H and H2)
constexpr size_t OFF_U1    = 137035776;               // 25,165,824 (QKV+VT | E)
constexpr size_t OFF_QKV   = OFF_U1;                  // 18,874,368
constexpr size_t OFF_VT    = OFF_U1 + 18874368;       //  6,291,456
constexpr size_t OFF_E     = OFF_U1;                  // 25,165,824
constexpr size_t OFF_SC    = 162201600;               //  8,388,608 (bf16 scores/AW in place)
constexpr size_t OFF_AO    = 170590208;               //  6,291,456
constexpr size_t OFF_XBF   = 176881664;               //  6,291,456
constexpr size_t OFF_PM    = 183173120;               //    524,288 (4096*32*4)
constexpr size_t OFF_PS    = 183697408;               //    524,288
constexpr size_t OFF_TLOG  = 184221696;               //     16,384
constexpr size_t OFF_ACC   = 184238080;               //         16
constexpr size_t WS_NEED   = 184238096;

extern "C" void kernel_launch(void* const* d_in, const int* in_sizes, int n_in,
                              void* d_out, int out_size, void* d_ws, size_t ws_size,
                              hipStream_t stream) {
  const int* idx = (const int*)d_in[0];
  const int* targets = (const int*)d_in[1];
  const float* wte = (const float*)d_in[2];
  const float* pos = (const float*)d_in[3];
  const float* dalpha = (const float*)d_in[4];
  const float* dytw = (const float*)d_in[5];
  const float* dytb = (const float*)d_in[6];
  const float* Wq = (const float*)d_in[7];
  const float* Wk = (const float*)d_in[8];
  const float* Wv = (const float*)d_in[9];
  const float* Wp = (const float*)d_in[10];
  const float* bp = (const float*)d_in[11];
  const float* We = (const float*)d_in[12];
  const float* be = (const float*)d_in[13];
  const float* Wc = (const float*)d_in[14];
  const float* bc = (const float*)d_in[15];
  float* out = (float*)d_out;

  if (ws_size < WS_NEED) return;
  char* ws = (char*)d_ws;
  short* WTEBF = (short*)(ws + OFF_WTEBF);
  short* LW = (short*)(ws + OFF_LW);     // [2][7077888]
  float* X = (float*)(ws + OFF_X);
  float* PRIOR = (float*)(ws + OFF_PRIOR);
  short* HB = (short*)(ws + OFF_HB);
  short* QKVB = (short*)(ws + OFF_QKV);
  short* VT = (short*)(ws + OFF_VT);
  short* E = (short*)(ws + OFF_E);
  short* SC = (short*)(ws + OFF_SC);     // bf16 scores, softmax in place
  short* AO = (short*)(ws + OFF_AO);
  short* XBF = (short*)(ws + OFF_XBF);
  float* PM = (float*)(ws + OFF_PM);
  float* PS = (float*)(ws + OFF_PS);
  float* TLOG = (float*)(ws + OFF_TLOG);
  double* ACC = (double*)(ws + OFF_ACC);

  hipMemsetAsync(ACC, 0, 16, stream);
  cvt_k<<<37728, 256, 0, stream>>>(wte, WTEBF, 9658368);
  cvt_layer_k<<<6912, 256, 0, stream>>>(Wq, Wk, Wv, Wp, We, Wc, LW);
  embed_head_k<<<3072, 256, 0, stream>>>(idx, wte, pos, dalpha, dytw, dytb, X, PRIOR, HB);

  const float scale = 0.03608439182435161f;  // 1/sqrt(768)

  for (int l = 0; l < 12; ++l) {
    const short* lw = LW + (long)(l & 1) * 7077888;
    // fused QKV: (4096x768) @ (2304x768)^T -> 4096x2304   (TN=64 grid-fill)
    gemm_bt<EP_BF16, 64><<<dim3(36, 32, 1), 256, 0, stream>>>(
        HB, lw, QKVB, 768, 768, 768, 2304, 0, 0, 0,
        nullptr, nullptr, nullptr, nullptr, nullptr, 0.f);
    // scores(bf16, no bias) = Q K^T * scale   (batched)
    gemm_bt<EP_SCORES, 64><<<dim3(16, 8, 4), 256, 0, stream>>>(
        QKVB, QKVB + 768, SC, 768, 2304, 2304, 1024,
        2359296, 2359296, 1048576, nullptr, nullptr, nullptr, nullptr, nullptr, scale);
    // softmax (bias reconstructed) + V transpose, one dispatch
    softmax_transp_k<<<4096, 256, 0, stream>>>(SC, QKVB, VT);
    // ao = aw @ V   (compact bf16 rows, stride 1024)
    gemm_bt<EP_BF16, 64><<<dim3(12, 8, 4), 256, 0, stream>>>(
        SC, VT, AO, 1024, 1024, 1024, 768, 1048576, 786432, 786432,
        nullptr, nullptr, nullptr, nullptr, nullptr, 0.f);
    // h2 = dyt2(ao @ Wp^T + bp)  -> HB
    gemm_bt<EP_DYT, 64><<<dim3(12, 32, 1), 256, 0, stream>>>(
        AO, lw + 1769472, HB, 768, 768, 768, 768, 0, 0, 0,
        bp + l * 768, dytw + l * 2304 + 768, dytb + l * 2304 + 768,
        dalpha + l * 3 + 1, nullptr, 0.f);
    // e = gelu(h2 @ We^T + be)   (TN=64 grid-fill)
    gemm_bt<EP_GELU, 64><<<dim3(48, 32, 1), 256, 0, stream>>>(
        HB, lw + 2359296, E, 768, 768, 768, 3072, 0, 0, 0,
        be + l * 3072, nullptr, nullptr, nullptr, nullptr, 0.f);
    // x = posterior = e @ Wc^T + bc + prior
    gemm_bt<EP_PRIOR, 64><<<dim3(12, 32, 1), 256, 0, stream>>>(
        E, lw + 4718592, X, 3072, 3072, 3072, 768, 0, 0, 0,
        bc + l * 768, nullptr, nullptr, nullptr, PRIOR, 0.f);
    // KL + next-layer head + next-layer weight cvt (l=11: emit XBF)
    tail_cvt_k<<<7936, 256, 0, stream>>>(
        PRIOR, X, pos + (l + 1) * 768, dalpha + (l + 1) * 3,
        dytw + (l + 1) * 2304, dytb + (l + 1) * 2304, HB, XBF, ACC, l == 11,
        Wq + (long)(l + 1) * 589824, Wk + (long)(l + 1) * 589824,
        Wv + (long)(l + 1) * 589824, Wp + (long)(l + 1) * 589824,
        We + (long)(l + 1) * 2359296, Wc + (long)(l + 1) * 2359296,
        (short*)(ws + OFF_LW) + (long)((l + 1) & 1) * 7077888);
  }

  lse_gemm_k<<<dim3(32, 32), 256, 0, stream>>>(XBF, WTEBF, PM, PS, out, 32);
  tlog_k<<<1024, 256, 0, stream>>>(XBF, WTEBF, targets, TLOG);
  stage2_k<<<16, 256, 0, stream>>>(PM, PS, TLOG, ACC, 32);
  finalize_k<<<1, 64, 0, stream>>>(ACC, out);
}

// Round 14
// 2965.213 us; speedup vs baseline: 1.0075x; 1.0075x over previous
//
#include <hip/hip_runtime.h>
#include <hip/hip_bf16.h>

// ---------- types & helpers ----------
typedef __attribute__((ext_vector_type(8))) short bf16x8;
typedef __attribute__((ext_vector_type(4))) float f32x4;

__device__ __forceinline__ short f2bf(float f) {
  unsigned u = __float_as_uint(f);
  u = u + 0x7fffu + ((u >> 16) & 1u);   // RNE
  return (short)(u >> 16);
}
__device__ __forceinline__ float bf2f(short s) {
  return __uint_as_float(((unsigned)(unsigned short)s) << 16);
}

#define GLOB_CAST(p) ((const __attribute__((address_space(1))) void*)(p))
#define LDS_CAST(p) ((__attribute__((address_space(3))) void*)(p))
#define GLL16(g, l) __builtin_amdgcn_global_load_lds(GLOB_CAST(g), LDS_CAST(l), 16, 0, 0)

constexpr int EP_BF16 = 0, EP_SCORES = 1, EP_DYT = 2, EP_GELU = 3, EP_PRIOR = 4;

// ---------- fp32 -> bf16 convert ----------
__global__ __launch_bounds__(256) void cvt_k(const float* __restrict__ src,
                                             short* __restrict__ dst, long n4) {
  const long s = (long)blockIdx.x * 256 + threadIdx.x;
  if (s >= n4) return;
  float4 v = ((const float4*)src)[s];
  short4 o = {f2bf(v.x), f2bf(v.y), f2bf(v.z), f2bf(v.w)};
  ((short4*)dst)[s] = o;
}

// convert one layer's 6 weight mats into contiguous bf16 buffer (layer 0 only;
// layers 1..11 are converted inside tail_cvt_k of the previous layer).
// Per-layer on purpose: LW written right before use stays L2/LLC-hot.
// (one-shot cvt_all was a persistent ~200us regression R5-R8: cold re-reads.)
__global__ __launch_bounds__(256) void cvt_layer_k(
    const float* __restrict__ wq, const float* __restrict__ wk,
    const float* __restrict__ wv, const float* __restrict__ wp,
    const float* __restrict__ we, const float* __restrict__ wc,
    short* __restrict__ dst) {
  const long s = (long)blockIdx.x * 256 + threadIdx.x;  // 1,769,472 total
  const long e = s * 4;
  const float* src; long off;
  if (e < 589824)        { src = wq; off = e; }
  else if (e < 1179648)  { src = wk; off = e - 589824; }
  else if (e < 1769472)  { src = wv; off = e - 1179648; }
  else if (e < 2359296)  { src = wp; off = e - 1769472; }
  else if (e < 4718592)  { src = we; off = e - 2359296; }
  else                   { src = wc; off = e - 4718592; }
  float4 v = *(const float4*)(src + off);
  short4 o = {f2bf(v.x), f2bf(v.y), f2bf(v.z), f2bf(v.w)};
  *(short4*)(dst + e) = o;
}

// ---------- embedding gather fused with layer-0 head ----------
__global__ __launch_bounds__(256) void embed_head_k(
    const int* __restrict__ idx, const float* __restrict__ wte,
    const float* __restrict__ pos, const float* __restrict__ alp,
    const float* __restrict__ w, const float* __restrict__ b,
    float* __restrict__ x, float* __restrict__ prior, short* __restrict__ h) {
  const long s = (long)blockIdx.x * 256 + threadIdx.x;  // 786432 float4 slots
  const long row = s / 192;
  const int c4 = (int)(s % 192);
  float4 xv = ((const float4*)(wte + (long)idx[row] * 768))[c4];
  ((float4*)x)[s] = xv;
  float4 pv = ((const float4*)pos)[c4];
  float4 w0 = ((const float4*)w)[c4];
  float4 b0 = ((const float4*)b)[c4];
  float4 w2 = ((const float4*)(w + 1536))[c4];
  float4 b2 = ((const float4*)(b + 1536))[c4];
  const float a0 = alp[0], a2 = alp[2];
  float4 xl = {xv.x + pv.x, xv.y + pv.y, xv.z + pv.z, xv.w + pv.w};
  float4 pr = {tanhf(a2 * xl.x) * w2.x + b2.x, tanhf(a2 * xl.y) * w2.y + b2.y,
               tanhf(a2 * xl.z) * w2.z + b2.z, tanhf(a2 * xl.w) * w2.w + b2.w};
  ((float4*)prior)[s] = pr;
  short4 hh = {f2bf(tanhf(a0 * xl.x) * w0.x + b0.x),
               f2bf(tanhf(a0 * xl.y) * w0.y + b0.y),
               f2bf(tanhf(a0 * xl.z) * w0.z + b0.z),
               f2bf(tanhf(a0 * xl.w) * w0.w + b0.w)};
  ((short4*)h)[s] = hh;
}

// ---------- generic C = A * B^T GEMM, 128xTN tile, BK=64 (R12-proven config) ----------
// T2 XOR-swizzled LDS both sides -> 0 bank conflicts (verified R2).
// TN choice (mapped R3/R6/R13): TN=64 only where TN=128 grid <512 blocks
// (N=768 shapes + batched attn); TN=128 for QKV/We (R13: TN=64 there -22us).
template <int EP, int TN>
__global__ __launch_bounds__(256, 2) void gemm_bt(
    const short* __restrict__ A, const short* __restrict__ B,
    void* __restrict__ Cv, int K, int lda, int ldb, int ldc,
    long sA, long sB, long sC,
    const float* __restrict__ bias, const float* __restrict__ dw,
    const float* __restrict__ db, const float* __restrict__ alp,
    const float* __restrict__ prior, float scale) {
  constexpr int NF = TN / 32;            // col frags per wave (4 or 2)
  __shared__ short As[128 * 64];
  __shared__ short Bs[TN * 64];
  const int tid = threadIdx.x, lane = tid & 63;
  const int wr = tid >> 7, wc = (tid >> 6) & 1;
  const long rowBase = (long)blockIdx.y * 128;
  const long colBase = (long)blockIdx.x * TN;
  const short* Ab = A + (long)blockIdx.z * sA;
  const short* Bb = B + (long)blockIdx.z * sB;
  const int srow = tid >> 3, sseg = tid & 7;
  const int ssegS = sseg ^ (srow & 7);    // pre-swizzled source column unit

  f32x4 acc[4][NF];
#pragma unroll
  for (int m = 0; m < 4; ++m)
#pragma unroll
    for (int n = 0; n < NF; ++n) acc[m][n] = (f32x4){0.f, 0.f, 0.f, 0.f};

  const int q = lane >> 4, cl = lane & 15;
  const int rsw = cl & 7;

  for (int kt = 0; kt < K; kt += 64) {
#pragma unroll
    for (int i = 0; i < 4; ++i)
      GLL16(Ab + (rowBase + i * 32 + srow) * (long)lda + kt + ssegS * 8,
            As + ((i * 32 + srow) * 64 + sseg * 8));
#pragma unroll
    for (int i = 0; i < TN / 32; ++i)
      GLL16(Bb + (colBase + i * 32 + srow) * (long)ldb + kt + ssegS * 8,
            Bs + ((i * 32 + srow) * 64 + sseg * 8));
    __syncthreads();
#pragma unroll
    for (int kk = 0; kk < 2; ++kk) {
      const int sw = ((kk * 4 + q) ^ rsw) << 3;   // swizzled short offset
      bf16x8 af[4], bfr[NF];
#pragma unroll
      for (int m = 0; m < 4; ++m)
        af[m] = *(const bf16x8*)&As[(wr * 64 + m * 16 + cl) * 64 + sw];
#pragma unroll
      for (int n = 0; n < NF; ++n)
        bfr[n] = *(const bf16x8*)&Bs[(wc * (TN / 2) + n * 16 + cl) * 64 + sw];
#pragma unroll
      for (int m = 0; m < 4; ++m)
#pragma unroll
        for (int n = 0; n < NF; ++n)
          acc[m][n] = __builtin_amdgcn_mfma_f32_16x16x32_bf16(af[m], bfr[n], acc[m][n], 0, 0, 0);
    }
    __syncthreads();
  }

#pragma unroll
  for (int m = 0; m < 4; ++m) {
#pragma unroll
    for (int n = 0; n < NF; ++n) {
#pragma unroll
      for (int j = 0; j < 4; ++j) {
        long r = rowBase + wr * 64 + m * 16 + q * 4 + j;
        long c = colBase + wc * (TN / 2) + n * 16 + cl;
        float v = acc[m][n][j];
        if constexpr (EP == EP_SCORES) {
          // bf16 of v*scale only (O(0.4), bf16-safe). ALiBi bias -|t-c| is
          // index-deterministic (up to -1023, NOT bf16-safe) and is
          // reconstructed exactly in softmax.
          ((short*)Cv)[(long)blockIdx.z * sC + r * ldc + c] = f2bf(v * scale);
        } else if constexpr (EP == EP_BF16) {
          ((short*)Cv)[(long)blockIdx.z * sC + r * ldc + c] = f2bf(v);
        } else if constexpr (EP == EP_DYT) {
          float xv = v + bias[c];
          ((short*)Cv)[r * (long)ldc + c] = f2bf(tanhf(alp[0] * xv) * dw[c] + db[c]);
        } else if constexpr (EP == EP_GELU) {
          float xv = v + bias[c];
          ((short*)Cv)[r * (long)ldc + c] = f2bf(0.5f * xv * (1.f + erff(xv * 0.70710678118654752f)));
        } else if constexpr (EP == EP_PRIOR) {
          ((float*)Cv)[r * (long)ldc + c] = v + bias[c] + prior[r * (long)ldc + c];
        }
      }
    }
  }
}

// ---------- fused: softmax (blocks 0..1023) + V transpose (blocks 1024..4095) ----------
__global__ __launch_bounds__(256) void softmax_transp_k(
    short* __restrict__ sc, const short* __restrict__ qkvb,
    short* __restrict__ vt) {
  if (blockIdx.x < 1024) {
    // softmax over 1024 bf16 scores, ALiBi bias reconstructed, in place
    const int lane = threadIdx.x & 63;
    const long row = (long)blockIdx.x * 4 + (threadIdx.x >> 6);
    const int t = (int)(row & 1023);
    short* p = sc + row * 1024;
    const int c0 = lane * 16;
    bf16x8 a = *(const bf16x8*)(p + c0);
    bf16x8 b = *(const bf16x8*)(p + c0 + 8);
    float v[16];
    float mx = -3e38f;
#pragma unroll
    for (int i = 0; i < 8; ++i) {
      v[i] = bf2f(a[i]) - fabsf((float)(t - (c0 + i)));
      v[i + 8] = bf2f(b[i]) - fabsf((float)(t - (c0 + 8 + i)));
    }
#pragma unroll
    for (int i = 0; i < 16; ++i) mx = fmaxf(mx, v[i]);
#pragma unroll
    for (int o = 1; o < 64; o <<= 1) mx = fmaxf(mx, __shfl_xor(mx, o));
    float e[16];
    float s = 0.f;
#pragma unroll
    for (int i = 0; i < 16; ++i) { e[i] = __expf(v[i] - mx); s += e[i]; }
#pragma unroll
    for (int o = 1; o < 64; o <<= 1) s += __shfl_xor(s, o);
    const float inv = 1.f / s;
    bf16x8 o0, o1;
#pragma unroll
    for (int i = 0; i < 8; ++i) {
      o0[i] = f2bf(e[i] * inv);
      o1[i] = f2bf(e[i + 8] * inv);
    }
    *(bf16x8*)(p + c0) = o0;
    *(bf16x8*)(p + c0 + 8) = o1;
  } else {
    // V transpose: (b,1024, cols 1536..2303 of QKVB) -> (b,768,1024)
    __shared__ short tbuf[32][33];
    const int t = blockIdx.x - 1024;          // 0..3071
    const int b = t & 3;
    const int rest = t >> 2;                  // 0..767
    const int d0 = (rest % 24) * 32, t0 = (rest / 24) * 32;
    const int tx = threadIdx.x & 31, ty = threadIdx.x >> 5;
    const short* Vb = qkvb + (long)b * 1024 * 2304 + 1536;
    short* Tb = vt + (long)b * 768 * 1024;
#pragma unroll
    for (int i = 0; i < 4; ++i)
      tbuf[ty + i * 8][tx] = Vb[(long)(t0 + ty + i * 8) * 2304 + d0 + tx];
    __syncthreads();
#pragma unroll
    for (int i = 0; i < 4; ++i)
      Tb[(long)(d0 + ty + i * 8) * 1024 + t0 + tx] = tbuf[tx][ty + i * 8];
  }
}

// ---------- fused tail: KL + next-layer head (blocks 0..1023) +
//            next-layer weight cvt (blocks 1024..7935) ----------
__global__ __launch_bounds__(256) void tail_cvt_k(
    float* __restrict__ prior, const float* __restrict__ post,
    const float* __restrict__ pos_n, const float* __restrict__ alp_n,
    const float* __restrict__ w_n, const float* __restrict__ b_n,
    short* __restrict__ h, short* __restrict__ xbf,
    double* __restrict__ acc, int last,
    const float* __restrict__ wq, const float* __restrict__ wk,
    const float* __restrict__ wv, const float* __restrict__ wp,
    const float* __restrict__ we, const float* __restrict__ wc,
    short* __restrict__ lwdst) {
  if (blockIdx.x >= 1024) {
    if (last) return;
    const long s = (long)(blockIdx.x - 1024) * 256 + threadIdx.x;  // 1,769,472
    const long e = s * 4;
    const float* src; long off;
    if (e < 589824)        { src = wq; off = e; }
    else if (e < 1179648)  { src = wk; off = e - 589824; }
    else if (e < 1769472)  { src = wv; off = e - 1179648; }
    else if (e < 2359296)  { src = wp; off = e - 1769472; }
    else if (e < 4718592)  { src = we; off = e - 2359296; }
    else                   { src = wc; off = e - 4718592; }
    float4 v = *(const float4*)(src + off);
    short4 o = {f2bf(v.x), f2bf(v.y), f2bf(v.z), f2bf(v.w)};
    *(short4*)(lwdst + e) = o;
    return;
  }
  const int lane = threadIdx.x & 63;
  const long row = (long)blockIdx.x * 4 + (threadIdx.x >> 6);
  float* pp = prior + row * 768;
  const float* qq = post + row * 768;
  float p[12], q[12];
#pragma unroll
  for (int i = 0; i < 12; ++i) { p[i] = pp[lane + i * 64]; q[i] = qq[lane + i * 64]; }
  float mp = -3e38f, mq = -3e38f, mm = -3e38f;
#pragma unroll
  for (int i = 0; i < 12; ++i) {
    float m = 0.5f * (p[i] + q[i]);
    mp = fmaxf(mp, p[i]); mq = fmaxf(mq, q[i]); mm = fmaxf(mm, m);
  }
#pragma unroll
  for (int o = 1; o < 64; o <<= 1) {
    mp = fmaxf(mp, __shfl_xor(mp, o));
    mq = fmaxf(mq, __shfl_xor(mq, o));
    mm = fmaxf(mm, __shfl_xor(mm, o));
  }
  float sp = 0.f, sq = 0.f, sm = 0.f;
#pragma unroll
  for (int i = 0; i < 12; ++i) {
    sp += __expf(p[i] - mp);
    sq += __expf(q[i] - mq);
    sm += __expf(0.5f * (p[i] + q[i]) - mm);
  }
#pragma unroll
  for (int o = 1; o < 64; o <<= 1) {
    sp += __shfl_xor(sp, o); sq += __shfl_xor(sq, o); sm += __shfl_xor(sm, o);
  }
  const float lseP = mp + logf(sp), lseQ = mq + logf(sq), lseM = mm + logf(sm);
  float kl = 0.f;
#pragma unroll
  for (int i = 0; i < 12; ++i) {
    float m = 0.5f * (p[i] + q[i]);
    float lm = m - lseM;
    kl += __expf(lm) * (2.f * lm - (p[i] - lseP) - (q[i] - lseQ));
  }
#pragma unroll
  for (int o = 1; o < 64; o <<= 1) kl += __shfl_xor(kl, o);
  if (lane == 0) atomicAdd(&acc[0], (double)kl);

  if (last) {
#pragma unroll
    for (int i = 0; i < 12; ++i) xbf[row * 768 + lane + i * 64] = f2bf(q[i]);
  } else {
    const float a0 = alp_n[0], a2 = alp_n[2];
#pragma unroll
    for (int i = 0; i < 12; ++i) {
      const int col = lane + i * 64;
      float xl = q[i] + pos_n[col];
      pp[col] = tanhf(a2 * xl) * w_n[1536 + col] + b_n[1536 + col];
      h[row * 768 + col] = f2bf(tanhf(a0 * xl) * w_n[col] + b_n[col]);
    }
  }
}

// ---------- vocab GEMM with online logsumexp + last-token logits ----------
// G=32 groups, grid (32,32)=1024 blocks = 4 blocks/CU (R12: occ 32->40%).
__global__ __launch_bounds__(256, 2) void lse_gemm_k(
    const short* __restrict__ Xb, const short* __restrict__ Wt,
    float* __restrict__ pm, float* __restrict__ ps,
    float* __restrict__ logits_out, int G) {
  __shared__ short As[128 * 64];
  __shared__ short Bs[128 * 64];
  __shared__ float pmx[2][128], psm[2][128], rm[128], rs[128];
  const int tid = threadIdx.x, lane = tid & 63;
  const int wr = tid >> 7, wc = (tid >> 6) & 1;
  const int g = blockIdx.x;
  const long rowBase = (long)blockIdx.y * 128;
  const int srow = tid >> 3, sseg = tid & 7;
  const int ssegS = sseg ^ (srow & 7);
  const int q = lane >> 4, cl = lane & 15;
  const int rsw = cl & 7;
  if (tid < 128) { rm[tid] = -3e38f; rs[tid] = 0.f; }

  for (int tile = g; tile < 393; tile += G) {
    const long colBase = (long)tile * 128;
    f32x4 acc[4][4];
#pragma unroll
    for (int m = 0; m < 4; ++m)
#pragma unroll
      for (int n = 0; n < 4; ++n) acc[m][n] = (f32x4){0.f, 0.f, 0.f, 0.f};

    for (int kt = 0; kt < 768; kt += 64) {
#pragma unroll
      for (int i = 0; i < 4; ++i) {
        GLL16(Xb + (rowBase + i * 32 + srow) * 768L + kt + ssegS * 8,
              As + ((i * 32 + srow) * 64 + sseg * 8));
        GLL16(Wt + (colBase + i * 32 + srow) * 768L + kt + ssegS * 8,
              Bs + ((i * 32 + srow) * 64 + sseg * 8));
      }
      __syncthreads();
#pragma unroll
      for (int kk = 0; kk < 2; ++kk) {
        const int sw = ((kk * 4 + q) ^ rsw) << 3;
        bf16x8 af[4], bfr[4];
#pragma unroll
        for (int m = 0; m < 4; ++m)
          af[m] = *(const bf16x8*)&As[(wr * 64 + m * 16 + cl) * 64 + sw];
#pragma unroll
        for (int n = 0; n < 4; ++n)
          bfr[n] = *(const bf16x8*)&Bs[(wc * 64 + n * 16 + cl) * 64 + sw];
#pragma unroll
        for (int m = 0; m < 4; ++m)
#pragma unroll
          for (int n = 0; n < 4; ++n)
            acc[m][n] = __builtin_amdgcn_mfma_f32_16x16x32_bf16(af[m], bfr[n], acc[m][n], 0, 0, 0);
      }
      __syncthreads();
    }

    // last-token logits straight to d_out
#pragma unroll
    for (int m = 0; m < 4; ++m)
#pragma unroll
      for (int n = 0; n < 4; ++n)
#pragma unroll
        for (int j = 0; j < 4; ++j) {
          long r = rowBase + wr * 64 + m * 16 + q * 4 + j;
          if ((r & 1023) == 1023) {
            long c = colBase + wc * 64 + n * 16 + cl;
            logits_out[(r >> 10) * 50304 + c] = acc[m][n][j];
          }
        }

    // per-row stats over this 128-col tile
#pragma unroll
    for (int m = 0; m < 4; ++m) {
#pragma unroll
      for (int j = 0; j < 4; ++j) {
        float mx = acc[m][0][j];
#pragma unroll
        for (int n = 1; n < 4; ++n) mx = fmaxf(mx, acc[m][n][j]);
#pragma unroll
        for (int o = 1; o < 16; o <<= 1) mx = fmaxf(mx, __shfl_xor(mx, o));
        float sm = 0.f;
#pragma unroll
        for (int n = 0; n < 4; ++n) sm += __expf(acc[m][n][j] - mx);
#pragma unroll
        for (int o = 1; o < 16; o <<= 1) sm += __shfl_xor(sm, o);
        if (cl == 0) {
          int lr = wr * 64 + m * 16 + q * 4 + j;
          pmx[wc][lr] = mx;
          psm[wc][lr] = sm;
        }
      }
    }
    __syncthreads();
    if (tid < 128) {
      float m0 = pmx[0][tid], m1 = pmx[1][tid];
      float m2 = fmaxf(m0, m1);
      float s2 = psm[0][tid] * __expf(m0 - m2) + psm[1][tid] * __expf(m1 - m2);
      float mo = rm[tid], mn = fmaxf(mo, m2);
      rs[tid] = rs[tid] * __expf(mo - mn) + s2 * __expf(m2 - mn);
      rm[tid] = mn;
    }
    __syncthreads();
  }
  if (tid < 128) {
    long row = rowBase + tid;
    pm[row * G + g] = rm[tid];
    ps[row * G + g] = rs[tid];
  }
}

// ---------- target logit: dot(x[row], wte[target[row]]) ----------
__global__ __launch_bounds__(256) void tlog_k(const short* __restrict__ xbf,
                                              const short* __restrict__ wtebf,
                                              const int* __restrict__ targets,
                                              float* __restrict__ tlog) {
  const int lane = threadIdx.x & 63;
  const long row = (long)blockIdx.x * 4 + (threadIdx.x >> 6);
  const long tgt = targets[row];
  const short* a = xbf + row * 768;
  const short* b = wtebf + tgt * 768;
  float s = 0.f;
#pragma unroll
  for (int i = 0; i < 12; ++i) s += bf2f(a[lane + i * 64]) * bf2f(b[lane + i * 64]);
#pragma unroll
  for (int o = 1; o < 64; o <<= 1) s += __shfl_xor(s, o);
  if (lane == 0) tlog[row] = s;
}

// ---------- combine split-lse partials, accumulate nll ----------
__global__ __launch_bounds__(256) void stage2_k(const float* __restrict__ pm,
                                                const float* __restrict__ ps,
                                                const float* __restrict__ tlog,
                                                double* __restrict__ acc, int G) {
  const long row = (long)blockIdx.x * 256 + threadIdx.x;
  float M = -3e38f;
  for (int gi = 0; gi < G; ++gi) M = fmaxf(M, pm[row * G + gi]);
  float S = 0.f;
  for (int gi = 0; gi < G; ++gi) S += ps[row * G + gi] * __expf(pm[row * G + gi] - M);
  float nll = (M + logf(S)) - tlog[row];
#pragma unroll
  for (int o = 1; o < 64; o <<= 1) nll += __shfl_xor(nll, o);
  if ((threadIdx.x & 63) == 0) atomicAdd(&acc[1], (double)nll);
}

__global__ void finalize_k(const double* __restrict__ acc, float* __restrict__ out) {
  if (threadIdx.x == 0)
    out[201216] = (float)(acc[1] / 4096.0 + 0.1 * 0.5 * acc[0] / 4.0);
}

// ---------- workspace layout (bytes) ----------
constexpr size_t OFF_WTEBF = 0;                       // 77,266,944
constexpr size_t OFF_LW    = 77266944;                // 2 x 14,155,776 (double-buffered)
constexpr size_t OFF_X     = 105578496;               // 12,582,912
constexpr size_t OFF_PRIOR = 118161408;               // 12,582,912
constexpr size_t OFF_HB    = 130744320;               //  6,291,456 (H and H2)
constexpr size_t OFF_U1    = 137035776;               // 25,165,824 (QKV+VT | E)
constexpr size_t OFF_QKV   = OFF_U1;                  // 18,874,368
constexpr size_t OFF_VT    = OFF_U1 + 18874368;       //  6,291,456
constexpr size_t OFF_E     = OFF_U1;                  // 25,165,824
constexpr size_t OFF_SC    = 162201600;               //  8,388,608 (bf16 scores/AW in place)
constexpr size_t OFF_AO    = 170590208;               //  6,291,456
constexpr size_t OFF_XBF   = 176881664;               //  6,291,456
constexpr size_t OFF_PM    = 183173120;               //    524,288 (4096*32*4)
constexpr size_t OFF_PS    = 183697408;               //    524,288
constexpr size_t OFF_TLOG  = 184221696;               //     16,384
constexpr size_t OFF_ACC   = 184238080;               //         16
constexpr size_t WS_NEED   = 184238096;

extern "C" void kernel_launch(void* const* d_in, const int* in_sizes, int n_in,
                              void* d_out, int out_size, void* d_ws, size_t ws_size,
                              hipStream_t stream) {
  const int* idx = (const int*)d_in[0];
  const int* targets = (const int*)d_in[1];
  const float* wte = (const float*)d_in[2];
  const float* pos = (const float*)d_in[3];
  const float* dalpha = (const float*)d_in[4];
  const float* dytw = (const float*)d_in[5];
  const float* dytb = (const float*)d_in[6];
  const float* Wq = (const float*)d_in[7];
  const float* Wk = (const float*)d_in[8];
  const float* Wv = (const float*)d_in[9];
  const float* Wp = (const float*)d_in[10];
  const float* bp = (const float*)d_in[11];
  const float* We = (const float*)d_in[12];
  const float* be = (const float*)d_in[13];
  const float* Wc = (const float*)d_in[14];
  const float* bc = (const float*)d_in[15];
  float* out = (float*)d_out;

  if (ws_size < WS_NEED) return;
  char* ws = (char*)d_ws;
  short* WTEBF = (short*)(ws + OFF_WTEBF);
  short* LW = (short*)(ws + OFF_LW);     // [2][7077888]
  float* X = (float*)(ws + OFF_X);
  float* PRIOR = (float*)(ws + OFF_PRIOR);
  short* HB = (short*)(ws + OFF_HB);
  short* QKVB = (short*)(ws + OFF_QKV);
  short* VT = (short*)(ws + OFF_VT);
  short* E = (short*)(ws + OFF_E);
  short* SC = (short*)(ws + OFF_SC);     // bf16 scores, softmax in place
  short* AO = (short*)(ws + OFF_AO);
  short* XBF = (short*)(ws + OFF_XBF);
  float* PM = (float*)(ws + OFF_PM);
  float* PS = (float*)(ws + OFF_PS);
  float* TLOG = (float*)(ws + OFF_TLOG);
  double* ACC = (double*)(ws + OFF_ACC);

  hipMemsetAsync(ACC, 0, 16, stream);
  cvt_k<<<37728, 256, 0, stream>>>(wte, WTEBF, 9658368);
  cvt_layer_k<<<6912, 256, 0, stream>>>(Wq, Wk, Wv, Wp, We, Wc, LW);
  embed_head_k<<<3072, 256, 0, stream>>>(idx, wte, pos, dalpha, dytw, dytb, X, PRIOR, HB);

  const float scale = 0.03608439182435161f;  // 1/sqrt(768)

  for (int l = 0; l < 12; ++l) {
    const short* lw = LW + (long)(l & 1) * 7077888;
    // fused QKV: (4096x768) @ (2304x768)^T -> 4096x2304
    gemm_bt<EP_BF16, 128><<<dim3(18, 32, 1), 256, 0, stream>>>(
        HB, lw, QKVB, 768, 768, 768, 2304, 0, 0, 0,
        nullptr, nullptr, nullptr, nullptr, nullptr, 0.f);
    // scores(bf16, no bias) = Q K^T * scale   (batched)
    gemm_bt<EP_SCORES, 64><<<dim3(16, 8, 4), 256, 0, stream>>>(
        QKVB, QKVB + 768, SC, 768, 2304, 2304, 1024,
        2359296, 2359296, 1048576, nullptr, nullptr, nullptr, nullptr, nullptr, scale);
    // softmax (bias reconstructed) + V transpose, one dispatch
    softmax_transp_k<<<4096, 256, 0, stream>>>(SC, QKVB, VT);
    // ao = aw @ V   (compact bf16 rows, stride 1024)
    gemm_bt<EP_BF16, 64><<<dim3(12, 8, 4), 256, 0, stream>>>(
        SC, VT, AO, 1024, 1024, 1024, 768, 1048576, 786432, 786432,
        nullptr, nullptr, nullptr, nullptr, nullptr, 0.f);
    // h2 = dyt2(ao @ Wp^T + bp)  -> HB
    gemm_bt<EP_DYT, 64><<<dim3(12, 32, 1), 256, 0, stream>>>(
        AO, lw + 1769472, HB, 768, 768, 768, 768, 0, 0, 0,
        bp + l * 768, dytw + l * 2304 + 768, dytb + l * 2304 + 768,
        dalpha + l * 3 + 1, nullptr, 0.f);
    // e = gelu(h2 @ We^T + be)
    gemm_bt<EP_GELU, 128><<<dim3(24, 32, 1), 256, 0, stream>>>(
        HB, lw + 2359296, E, 768, 768, 768, 3072, 0, 0, 0,
        be + l * 3072, nullptr, nullptr, nullptr, nullptr, 0.f);
    // x = posterior = e @ Wc^T + bc + prior
    gemm_bt<EP_PRIOR, 64><<<dim3(12, 32, 1), 256, 0, stream>>>(
        E, lw + 4718592, X, 3072, 3072, 3072, 768, 0, 0, 0,
        bc + l * 768, nullptr, nullptr, nullptr, PRIOR, 0.f);
    // KL + next-layer head + next-layer weight cvt (l=11: emit XBF)
    tail_cvt_k<<<7936, 256, 0, stream>>>(
        PRIOR, X, pos + (l + 1) * 768, dalpha + (l + 1) * 3,
        dytw + (l + 1) * 2304, dytb + (l + 1) * 2304, HB, XBF, ACC, l == 11,
        Wq + (long)(l + 1) * 589824, Wk + (long)(l + 1) * 589824,
        Wv + (long)(l + 1) * 589824, Wp + (long)(l + 1) * 589824,
        We + (long)(l + 1) * 2359296, Wc + (long)(l + 1) * 2359296,
        (short*)(ws + OFF_LW) + (long)((l + 1) & 1) * 7077888);
  }

  lse_gemm_k<<<dim3(32, 32), 256, 0, stream>>>(XBF, WTEBF, PM, PS, out, 32);
  tlog_k<<<1024, 256, 0, stream>>>(XBF, WTEBF, targets, TLOG);
  stage2_k<<<16, 256, 0, stream>>>(PM, PS, TLOG, ACC, 32);
  finalize_k<<<1, 64, 0, stream>>>(ACC, out);
}